// Round 6
// baseline (268.977 us; speedup 1.0000x reference)
//
#include <hip/hip_runtime.h>

// MambaSkipConnection: B=4, C=192, H=W=64 (L=4096), DI=384, N=16, RK=12, DCONV=4
// Round 6: scan1/scan2 rewritten for LDS-pipe economy: [d][t]-major b128 reads,
// DPP quad-reduction + pq transpose (no pbuf), self-loaded dt-dot, 2 barriers/sub.
// Workspace usage: 19,761,152 floats = 79.0 MB.

#define Bn 4
#define Cn 192
#define Hn 64
#define Wn 64
#define Ln 4096
#define DIn 384
#define Nst 16
#define RK 12
#define E2 768
#define NCn 64
#define EPSf 1e-5f

typedef __bf16 bf16x8 __attribute__((ext_vector_type(8)));
typedef float f32x4 __attribute__((ext_vector_type(4)));
typedef unsigned short u16;
typedef unsigned int u32;

static __device__ __forceinline__ float sigmoidf_(float v) {
    return 1.f / (1.f + __expf(-v));
}
static __device__ __forceinline__ float softplusf_(float v) {
    return v > 20.f ? v : log1pf(__expf(v));
}
static __device__ __forceinline__ u16 f2bf(float f) {
    u32 u = __float_as_uint(f);
    u32 r = (u + 0x7FFFu + ((u >> 16) & 1u)) >> 16;
    return (u16)r;
}
static __device__ __forceinline__ float bf2f(u16 v) {
    return __uint_as_float(((u32)v) << 16);
}

// ---------------------------------------------------------------- K1: LayerNorm -> bf16 tokens
__global__ __launch_bounds__(256) void k_ln(const float* __restrict__ x,
                                            const float* __restrict__ lnw,
                                            const float* __restrict__ lnb,
                                            u16* __restrict__ tn_bf) {
    __shared__ float tile[Cn][65];
    __shared__ float red[2][4][64];
    __shared__ float mean_s[64], rstd_s[64];
    int b = blockIdx.x >> 6;
    int l0 = (blockIdx.x & 63) << 6;
    int tid = threadIdx.x;
    for (int idx = tid; idx < Cn * 64; idx += 256) {
        int c = idx >> 6, ll = idx & 63;
        tile[c][ll] = x[((size_t)(b * Cn + c) << 12) + l0 + ll];
    }
    __syncthreads();
    int ll = tid & 63, grp = tid >> 6;
    float s = 0.f, s2 = 0.f;
    for (int c = grp * 48; c < grp * 48 + 48; ++c) {
        float v = tile[c][ll];
        s += v; s2 += v * v;
    }
    red[0][grp][ll] = s; red[1][grp][ll] = s2;
    __syncthreads();
    if (tid < 64) {
        float m = red[0][0][tid] + red[0][1][tid] + red[0][2][tid] + red[0][3][tid];
        float q = red[1][0][tid] + red[1][1][tid] + red[1][2][tid] + red[1][3][tid];
        m *= (1.f / Cn);
        float var = q * (1.f / Cn) - m * m;
        mean_s[tid] = m;
        rstd_s[tid] = rsqrtf(var + EPSf);
    }
    __syncthreads();
    for (int idx = tid; idx < 64 * Cn; idx += 256) {
        int t = idx / Cn, c = idx - t * Cn;
        float v = (tile[c][t] - mean_s[t]) * rstd_s[t] * lnw[c] + lnb[c];
        tn_bf[(size_t)(b * Ln + l0 + t) * Cn + c] = f2bf(v);
    }
}

// ---------------------------------------------------------------- K2: generic bf16 MFMA GEMM
template <int BM, int BN, int K, int BK, int NR, int LDO, bool BOUT>
__global__ __launch_bounds__(256) void k_bgemm(const u16* __restrict__ A,
                                               const float* __restrict__ W,
                                               void* __restrict__ outv) {
    constexpr int PK = BK + 8;
    constexpr int MF = BM / 64;
    constexpr int NF = BN / 16;
    constexpr int NCH = BK / 8;
    constexpr int NQ = BK / 4;
    __shared__ __align__(16) u16 As[BM * PK];
    __shared__ __align__(16) u16 Ws_[BN * PK];
    int m0 = blockIdx.x * BM, n0 = blockIdx.y * BN;
    int tid = threadIdx.x;
    int wid = tid >> 6, lane = tid & 63;
    int lrow = lane & 15, lk8 = (lane >> 4) << 3, rowq = lane >> 4;
    f32x4 acc[MF][NF];
#pragma unroll
    for (int i = 0; i < MF; ++i)
#pragma unroll
        for (int j = 0; j < NF; ++j) acc[i][j] = (f32x4){0.f, 0.f, 0.f, 0.f};
    for (int kt = 0; kt < K / BK; ++kt) {
        int k0 = kt * BK;
        for (int idx = tid; idx < BM * NCH; idx += 256) {
            int r = idx / NCH, c2 = idx - r * NCH;
            *(uint4*)&As[r * PK + c2 * 8] =
                *(const uint4*)&A[(size_t)(m0 + r) * K + k0 + c2 * 8];
        }
        for (int idx = tid; idx < BN * NQ; idx += 256) {
            int r = idx / NQ, q = idx - r * NQ;
            ushort4 o = make_ushort4(0, 0, 0, 0);
            if (NR == BN || r < NR) {
                float4 v = *(const float4*)&W[(size_t)(n0 + r) * K + k0 + q * 4];
                o.x = f2bf(v.x); o.y = f2bf(v.y); o.z = f2bf(v.z); o.w = f2bf(v.w);
            }
            *(ushort4*)&Ws_[r * PK + q * 4] = o;
        }
        __syncthreads();
#pragma unroll
        for (int ks = 0; ks < BK / 32; ++ks) {
            bf16x8 a[MF], bfr[NF];
#pragma unroll
            for (int mf = 0; mf < MF; ++mf)
                a[mf] = *(const bf16x8*)&As[(wid * (BM / 4) + mf * 16 + lrow) * PK + ks * 32 + lk8];
#pragma unroll
            for (int nf = 0; nf < NF; ++nf)
                bfr[nf] = *(const bf16x8*)&Ws_[(nf * 16 + lrow) * PK + ks * 32 + lk8];
#pragma unroll
            for (int mf = 0; mf < MF; ++mf)
#pragma unroll
                for (int nf = 0; nf < NF; ++nf)
                    acc[mf][nf] = __builtin_amdgcn_mfma_f32_16x16x32_bf16(a[mf], bfr[nf],
                                                                          acc[mf][nf], 0, 0, 0);
        }
        __syncthreads();
    }
#pragma unroll
    for (int mf = 0; mf < MF; ++mf)
#pragma unroll
        for (int nf = 0; nf < NF; ++nf) {
            int col = n0 + nf * 16 + lrow;
            if (NR != BN && col >= NR) continue;
            int rbase = m0 + wid * (BM / 4) + mf * 16 + rowq * 4;
#pragma unroll
            for (int r = 0; r < 4; ++r) {
                if (BOUT)
                    ((u16*)outv)[(size_t)(rbase + r) * LDO + col] = f2bf(acc[mf][nf][r]);
                else
                    ((float*)outv)[(size_t)(rbase + r) * LDO + col] = acc[mf][nf][r];
            }
        }
}

// ---------------------------------------------------------------- K3: causal depthwise conv1d + SiLU (bf16 in/out)
__global__ __launch_bounds__(256) void k_conv1d(const u16* __restrict__ xz,
                                                const float* __restrict__ cw,
                                                const float* __restrict__ cb,
                                                u16* __restrict__ xt_bf) {
    int g = blockIdx.x * 256 + threadIdx.x;
    int m = g / 96, dq = g - m * 96;
    int d = dq << 2;
    int l = m & (Ln - 1);
    float w_[4][4];
    *(float4*)&w_[0][0] = *(const float4*)&cw[(d + 0) << 2];
    *(float4*)&w_[1][0] = *(const float4*)&cw[(d + 1) << 2];
    *(float4*)&w_[2][0] = *(const float4*)&cw[(d + 2) << 2];
    *(float4*)&w_[3][0] = *(const float4*)&cw[(d + 3) << 2];
    float4 bv = *(const float4*)&cb[d];
    float o_[4] = {bv.x, bv.y, bv.z, bv.w};
    const u16* base = xz + (size_t)m * E2 + d;
#pragma unroll
    for (int j = 0; j < 4; ++j) {
        if (l >= j) {
            ushort4 in4 = *(const ushort4*)(base - (size_t)j * E2);
            o_[0] += bf2f(in4.x) * w_[0][3 - j];
            o_[1] += bf2f(in4.y) * w_[1][3 - j];
            o_[2] += bf2f(in4.z) * w_[2][3 - j];
            o_[3] += bf2f(in4.w) * w_[3][3 - j];
        }
    }
    ushort4 rb;
    rb.x = f2bf(o_[0] * sigmoidf_(o_[0]));
    rb.y = f2bf(o_[1] * sigmoidf_(o_[1]));
    rb.z = f2bf(o_[2] * sigmoidf_(o_[2]));
    rb.w = f2bf(o_[3] * sigmoidf_(o_[3]));
    *(ushort4*)&xt_bf[(size_t)m * DIn + d] = rb;
}

// ---------------------------------------------------------------- K6a: scan pass 1 (dt_proj fused; [d][t] LDS, b128 reads)
__global__ __launch_bounds__(256) void k_scan1(const u16* __restrict__ xt_bf,
                                               const float* __restrict__ dbl,
                                               const float* __restrict__ dtw,
                                               const float* __restrict__ dtb,
                                               const float* __restrict__ alog,
                                               float* __restrict__ chunkA,
                                               float* __restrict__ chunkH) {
    __shared__ __align__(16) float ds_de[16][20], ds_dux[16][20], ds_bt[16][20];
    int dg = blockIdx.x, c = blockIdx.y, b = blockIdx.z;
    int tid = threadIdx.x;
    int dl = tid >> 4, n = tid & 15;     // compute role
    int trow = tid >> 4, dd = tid & 15;  // staging role (same bits)
    float Av = -__expf(alog[(dg * 16 + dl) * Nst + n]);
    float dtwr[12];
    *(float4*)&dtwr[0] = *(const float4*)&dtw[(dg * 16 + dd) * RK + 0];
    *(float4*)&dtwr[4] = *(const float4*)&dtw[(dg * 16 + dd) * RK + 4];
    *(float4*)&dtwr[8] = *(const float4*)&dtw[(dg * 16 + dd) * RK + 8];
    float dtbr = dtb[dg * 16 + dd];
    float h = 0.f, ap = 1.f;
    for (int sub = 0; sub < 4; ++sub) {
        int row = b * Ln + c * 64 + sub * 16 + trow;
        float4 q0 = *(const float4*)&dbl[(size_t)row * 44 + 0];
        float4 q1 = *(const float4*)&dbl[(size_t)row * 44 + 4];
        float4 q2 = *(const float4*)&dbl[(size_t)row * 44 + 8];
        float uu = bf2f(xt_bf[(size_t)row * DIn + dg * 16 + dd]);
        float bbv = dbl[(size_t)row * 44 + 12 + dd];
        float acc = dtbr;
        acc = fmaf(q0.x, dtwr[0], acc); acc = fmaf(q0.y, dtwr[1], acc);
        acc = fmaf(q0.z, dtwr[2], acc); acc = fmaf(q0.w, dtwr[3], acc);
        acc = fmaf(q1.x, dtwr[4], acc); acc = fmaf(q1.y, dtwr[5], acc);
        acc = fmaf(q1.z, dtwr[6], acc); acc = fmaf(q1.w, dtwr[7], acc);
        acc = fmaf(q2.x, dtwr[8], acc); acc = fmaf(q2.y, dtwr[9], acc);
        acc = fmaf(q2.z, dtwr[10], acc); acc = fmaf(q2.w, dtwr[11], acc);
        float de = softplusf_(acc);
        ds_de[dd][trow] = de;
        ds_dux[dd][trow] = de * uu;
        ds_bt[dd][trow] = bbv;
        __syncthreads();
#pragma unroll
        for (int t4 = 0; t4 < 4; ++t4) {
            f32x4 de4 = *(const f32x4*)&ds_de[dl][t4 * 4];
            f32x4 dux4 = *(const f32x4*)&ds_dux[dl][t4 * 4];
            f32x4 bb4 = *(const f32x4*)&ds_bt[n][t4 * 4];
#pragma unroll
            for (int j = 0; j < 4; ++j) {
                float a = __expf(de4[j] * Av);
                ap *= a;
                h = fmaf(a, h, dux4[j] * bb4[j]);
            }
        }
        __syncthreads();
    }
    size_t base = (size_t)(b * NCn + c) * (DIn * Nst) + dg * 256;
    chunkA[base + tid] = ap;
    chunkH[base + tid] = h;
}

// ---------------------------------------------------------------- K6b: scan pass 1.5 — chunk-start states
__global__ __launch_bounds__(256) void k_scan15(const float* __restrict__ chunkA,
                                                const float* __restrict__ chunkH,
                                                float* __restrict__ hstart) {
    int dg = blockIdx.x, b = blockIdx.y;
    int tid = threadIdx.x;
    size_t off = (size_t)b * NCn * (DIn * Nst) + dg * 256 + tid;
    float h = 0.f;
    for (int c0 = 0; c0 < NCn; c0 += 8) {
        float Ar[8], Hr[8];
#pragma unroll
        for (int j = 0; j < 8; ++j) {
            Ar[j] = chunkA[off + (size_t)(c0 + j) * (DIn * Nst)];
            Hr[j] = chunkH[off + (size_t)(c0 + j) * (DIn * Nst)];
        }
#pragma unroll
        for (int j = 0; j < 8; ++j) {
            hstart[off + (size_t)(c0 + j) * (DIn * Nst)] = h;
            h = fmaf(Ar[j], h, Hr[j]);
        }
    }
}

// ---------------------------------------------------------------- K6c: scan pass 2 (dt_proj + gate fused; DPP reduce + pq)
__global__ __launch_bounds__(256) void k_scan2(const u16* __restrict__ xt_bf,
                                               const float* __restrict__ dbl,
                                               const float* __restrict__ dtw,
                                               const float* __restrict__ dtb,
                                               const float* __restrict__ alog,
                                               const float* __restrict__ hstart,
                                               const u16* __restrict__ xz,
                                               const float* __restrict__ Dp,
                                               u16* __restrict__ agate) {
    __shared__ __align__(16) float ds_de[16][20], ds_dux[16][20], ds_bt[16][20], ds_ct[16][20];
    __shared__ __align__(16) float pq[16][16][4];
    int dg = blockIdx.x, c = blockIdx.y, b = blockIdx.z;
    int tid = threadIdx.x;
    int dl = tid >> 4, n = tid & 15;
    int trow = tid >> 4, dd = tid & 15;
    int aq = n >> 2, bq = n & 3;
    float Av = -__expf(alog[(dg * 16 + dl) * Nst + n]);
    float dtwr[12];
    *(float4*)&dtwr[0] = *(const float4*)&dtw[(dg * 16 + dd) * RK + 0];
    *(float4*)&dtwr[4] = *(const float4*)&dtw[(dg * 16 + dd) * RK + 4];
    *(float4*)&dtwr[8] = *(const float4*)&dtw[(dg * 16 + dd) * RK + 8];
    float dtbr = dtb[dg * 16 + dd];
    float Dr = Dp[dg * 16 + dd];
    size_t base = (size_t)(b * NCn + c) * (DIn * Nst) + dg * 256;
    float h = hstart[base + tid];
    for (int sub = 0; sub < 4; ++sub) {
        int row = b * Ln + c * 64 + sub * 16 + trow;
        float4 q0 = *(const float4*)&dbl[(size_t)row * 44 + 0];
        float4 q1 = *(const float4*)&dbl[(size_t)row * 44 + 4];
        float4 q2 = *(const float4*)&dbl[(size_t)row * 44 + 8];
        float uu = bf2f(xt_bf[(size_t)row * DIn + dg * 16 + dd]);
        float zz = bf2f(xz[(size_t)row * E2 + DIn + dg * 16 + dd]);
        float bbv = dbl[(size_t)row * 44 + 12 + dd];
        float ctv = dbl[(size_t)row * 44 + 28 + dd];
        float acc = dtbr;
        acc = fmaf(q0.x, dtwr[0], acc); acc = fmaf(q0.y, dtwr[1], acc);
        acc = fmaf(q0.z, dtwr[2], acc); acc = fmaf(q0.w, dtwr[3], acc);
        acc = fmaf(q1.x, dtwr[4], acc); acc = fmaf(q1.y, dtwr[5], acc);
        acc = fmaf(q1.z, dtwr[6], acc); acc = fmaf(q1.w, dtwr[7], acc);
        acc = fmaf(q2.x, dtwr[8], acc); acc = fmaf(q2.y, dtwr[9], acc);
        acc = fmaf(q2.z, dtwr[10], acc); acc = fmaf(q2.w, dtwr[11], acc);
        float de = softplusf_(acc);
        ds_de[dd][trow] = de;
        ds_dux[dd][trow] = de * uu;
        ds_bt[dd][trow] = bbv;
        ds_ct[dd][trow] = ctv;
        __syncthreads();
        float P[4] = {0.f, 0.f, 0.f, 0.f};
#pragma unroll
        for (int t4 = 0; t4 < 4; ++t4) {
            f32x4 de4 = *(const f32x4*)&ds_de[dl][t4 * 4];
            f32x4 dux4 = *(const f32x4*)&ds_dux[dl][t4 * 4];
            f32x4 bb4 = *(const f32x4*)&ds_bt[n][t4 * 4];
            f32x4 ct4 = *(const f32x4*)&ds_ct[n][t4 * 4];
#pragma unroll
            for (int j = 0; j < 4; ++j) {
                float a = __expf(de4[j] * Av);
                h = fmaf(a, h, dux4[j] * bb4[j]);
                float p = h * ct4[j];
                p += __shfl_xor(p, 1);
                p += __shfl_xor(p, 2);   // quad partial (over n within quad)
                P[t4] = (bq == j) ? p : P[t4];
            }
        }
        // lane (dl, n=4*aq+bq) holds quad-aq partial for tokens {bq,4+bq,8+bq,12+bq}
#pragma unroll
        for (int tt = 0; tt < 4; ++tt)
            pq[tt * 4 + bq][dl][aq] = P[tt];
        __syncthreads();
        // gate + store by staging-role thread (token trow, channel dd)
        f32x4 p4 = *(const f32x4*)&pq[trow][dd][0];
        float y = (p4[0] + p4[1]) + (p4[2] + p4[3]);
        float ga = (y + uu * Dr) * (zz * sigmoidf_(zz));
        agate[(size_t)row * DIn + dg * 16 + dd] = f2bf(ga);
    }
}

// ---------------------------------------------------------------- K7: out_proj GEMM (bf16 A) + residual -> t2bf
__global__ __launch_bounds__(256) void k_outproj(const u16* __restrict__ agate,
                                                 const float* __restrict__ Wo,
                                                 const float* __restrict__ x,
                                                 u16* __restrict__ t2bf) {
    constexpr int BM = 128, BN = 64, K = DIn, BK = 96;
    constexpr int PK = BK + 8;
    constexpr int NCH = BK / 8;
    constexpr int NQ = BK / 4;
    __shared__ __align__(16) u16 As[BM * PK];
    __shared__ __align__(16) u16 Ws_[BN * PK];
    int m0 = blockIdx.x * BM, n0 = blockIdx.y * BN;
    int tid = threadIdx.x;
    int wid = tid >> 6, lane = tid & 63;
    int lrow = lane & 15, lk8 = (lane >> 4) << 3, rowq = lane >> 4;
    f32x4 acc[2][4];
#pragma unroll
    for (int i = 0; i < 2; ++i)
#pragma unroll
        for (int j = 0; j < 4; ++j) acc[i][j] = (f32x4){0.f, 0.f, 0.f, 0.f};
    for (int kt = 0; kt < K / BK; ++kt) {
        int k0 = kt * BK;
        for (int idx = tid; idx < BM * NCH; idx += 256) {
            int r = idx / NCH, c2 = idx - r * NCH;
            *(uint4*)&As[r * PK + c2 * 8] =
                *(const uint4*)&agate[(size_t)(m0 + r) * K + k0 + c2 * 8];
        }
        for (int idx = tid; idx < BN * NQ; idx += 256) {
            int r = idx / NQ, q = idx - r * NQ;
            float4 v = *(const float4*)&Wo[(size_t)(n0 + r) * K + k0 + q * 4];
            ushort4 o;
            o.x = f2bf(v.x); o.y = f2bf(v.y); o.z = f2bf(v.z); o.w = f2bf(v.w);
            *(ushort4*)&Ws_[r * PK + q * 4] = o;
        }
        __syncthreads();
#pragma unroll
        for (int ks = 0; ks < BK / 32; ++ks) {
            bf16x8 a[2], bfr[4];
#pragma unroll
            for (int mf = 0; mf < 2; ++mf)
                a[mf] = *(const bf16x8*)&As[(wid * 32 + mf * 16 + lrow) * PK + ks * 32 + lk8];
#pragma unroll
            for (int nf = 0; nf < 4; ++nf)
                bfr[nf] = *(const bf16x8*)&Ws_[(nf * 16 + lrow) * PK + ks * 32 + lk8];
#pragma unroll
            for (int mf = 0; mf < 2; ++mf)
#pragma unroll
                for (int nf = 0; nf < 4; ++nf)
                    acc[mf][nf] = __builtin_amdgcn_mfma_f32_16x16x32_bf16(a[mf], bfr[nf],
                                                                          acc[mf][nf], 0, 0, 0);
        }
        __syncthreads();
    }
#pragma unroll
    for (int mf = 0; mf < 2; ++mf)
#pragma unroll
        for (int nf = 0; nf < 4; ++nf) {
            int col = n0 + nf * 16 + lrow;
            int rbase = m0 + wid * 32 + mf * 16 + rowq * 4;
#pragma unroll
            for (int r = 0; r < 4; ++r) {
                int m = rbase + r;
                int b = m >> 12, l = m & 4095;
                float v = acc[mf][nf][r] + x[((size_t)(b * Cn + col) << 12) + l];
                t2bf[(size_t)m * Cn + col] = f2bf(v);
            }
        }
}

// ---------------------------------------------------------------- K8a: rfw fp32 [co][ci][tap] -> bf16 [tap][co][ci]
__global__ __launch_bounds__(256) void k_cvt_rfw(const float* __restrict__ rfw,
                                                 u16* __restrict__ wcv) {
    int g = blockIdx.x * 256 + threadIdx.x;
    if (g >= Cn * Cn * 9) return;
    int tap = g / (Cn * Cn);
    int rem = g - tap * (Cn * Cn);
    int co = rem / Cn, ci = rem - co * Cn;
    wcv[g] = f2bf(rfw[((size_t)co * Cn + ci) * 9 + tap]);
}

// ---------------------------------------------------------------- K8: conv3x3 + BN + ReLU, bf16 MFMA implicit GEMM
__global__ __launch_bounds__(256) void k_conv3(const u16* __restrict__ t2bf,
                                               const u16* __restrict__ wcv,
                                               const float* __restrict__ rfb,
                                               const float* __restrict__ bnw,
                                               const float* __restrict__ bnb,
                                               const float* __restrict__ bnm,
                                               const float* __restrict__ bnv,
                                               float* __restrict__ out) {
    __shared__ __align__(16) u16 in_s[4 * 66 * 40];
    __shared__ __align__(16) u16 w_s[9 * 64 * 40];
    int mt = blockIdx.x;
    int n0 = blockIdx.y << 6;
    int b = mt >> 5;
    int h0 = (mt & 31) << 1;
    int hw0 = h0 << 6;
    int tid = threadIdx.x;
    int wid = tid >> 6, lane = tid & 63;
    int lrow = lane & 15, lk8 = (lane >> 4) << 3, l4 = (lane >> 4) << 2;

    for (int idx = tid; idx < 4 * 40; idx += 256) {
        int rl = idx / 40, k = idx - rl * 40;
        in_s[(rl * 66 + 0) * 40 + k] = 0;
        in_s[(rl * 66 + 65) * 40 + k] = 0;
    }

    int s0 = wid * 32 + lrow;
    int s1 = s0 + 16;
    int abase0 = ((s0 >> 6) * 66 + (s0 & 63)) * 40 + lk8;
    int abase1 = ((s1 >> 6) * 66 + (s1 & 63)) * 40 + lk8;
    int bbase = lrow * 40 + lk8;

    f32x4 acc[2][4];
#pragma unroll
    for (int i = 0; i < 2; ++i)
#pragma unroll
        for (int j = 0; j < 4; ++j) acc[i][j] = (f32x4){0.f, 0.f, 0.f, 0.f};

    int wq = tid >> 2, cq = (tid & 3) << 3;
    for (int ci0 = 0; ci0 < Cn; ci0 += 32) {
        __syncthreads();
#pragma unroll
        for (int rl = 0; rl < 4; ++rl) {
            int gr = h0 - 1 + rl;
            uint4 v = make_uint4(0u, 0u, 0u, 0u);
            if (gr >= 0 && gr < Hn)
                v = *(const uint4*)&t2bf[(size_t)((b << 12) + (gr << 6) + wq) * Cn + ci0 + cq];
            *(uint4*)&in_s[(rl * 66 + wq + 1) * 40 + cq] = v;
        }
#pragma unroll
        for (int tap = 0; tap < 9; ++tap) {
            int co = tid >> 2;
            uint4 v = *(const uint4*)&wcv[((size_t)tap * Cn + n0 + co) * Cn + ci0 + cq];
            *(uint4*)&w_s[(tap * 64 + co) * 40 + cq] = v;
        }
        __syncthreads();
#pragma unroll
        for (int kh = 0; kh < 3; ++kh) {
#pragma unroll
            for (int kw = 0; kw < 3; ++kw) {
                int aoff = (kh * 66 + kw) * 40;
                bf16x8 a0 = *(const bf16x8*)&in_s[abase0 + aoff];
                bf16x8 a1 = *(const bf16x8*)&in_s[abase1 + aoff];
                int boff = (kh * 3 + kw) * 2560;
#pragma unroll
                for (int nf = 0; nf < 4; ++nf) {
                    bf16x8 bb = *(const bf16x8*)&w_s[bbase + nf * 640 + boff];
                    acc[0][nf] = __builtin_amdgcn_mfma_f32_16x16x32_bf16(a0, bb, acc[0][nf], 0, 0, 0);
                    acc[1][nf] = __builtin_amdgcn_mfma_f32_16x16x32_bf16(a1, bb, acc[1][nf], 0, 0, 0);
                }
            }
        }
    }
#pragma unroll
    for (int nf = 0; nf < 4; ++nf) {
        int co = n0 + nf * 16 + lrow;
        float sc = bnw[co] * rsqrtf(bnv[co] + EPSf);
        float sf = (rfb[co] - bnm[co]) * sc + bnb[co];
        size_t obase = ((size_t)(b * Cn + co) << 12) + hw0;
#pragma unroll
        for (int mf = 0; mf < 2; ++mf) {
            int sb = wid * 32 + mf * 16 + l4;
            float4 o;
            o.x = fmaxf(acc[mf][nf][0] * sc + sf, 0.f);
            o.y = fmaxf(acc[mf][nf][1] * sc + sf, 0.f);
            o.z = fmaxf(acc[mf][nf][2] * sc + sf, 0.f);
            o.w = fmaxf(acc[mf][nf][3] * sc + sf, 0.f);
            *(float4*)&out[obase + sb] = o;
        }
    }
}

// ----------------------------------------------------------------
extern "C" void kernel_launch(void* const* d_in, const int* in_sizes, int n_in,
                              void* d_out, int out_size, void* d_ws, size_t ws_size,
                              hipStream_t stream) {
    const float* x    = (const float*)d_in[0];
    const float* lnw  = (const float*)d_in[1];
    const float* lnb  = (const float*)d_in[2];
    const float* inpw = (const float*)d_in[3];
    const float* cw   = (const float*)d_in[4];
    const float* cb   = (const float*)d_in[5];
    const float* xpw  = (const float*)d_in[6];
    const float* dtw  = (const float*)d_in[7];
    const float* dtb  = (const float*)d_in[8];
    const float* alog = (const float*)d_in[9];
    const float* Dp   = (const float*)d_in[10];
    const float* Wo   = (const float*)d_in[11];
    const float* rfw  = (const float*)d_in[12];
    const float* rfb  = (const float*)d_in[13];
    const float* bnw  = (const float*)d_in[14];
    const float* bnb  = (const float*)d_in[15];
    const float* bnm  = (const float*)d_in[16];
    const float* bnv  = (const float*)d_in[17];

    float* ws = (float*)d_ws;
    // region map (floats):
    // [0 .. 1572864)          tn_bf (bf16, ln->inproj) -> t2bf (bf16, outproj->conv3)
    // [1572864 .. 3145728)    hstart (scan15->scan2)
    // [3145728 .. 9437184)    xz (bf16, 16384x768)
    // [9437184 .. 12582912)   xt_bf (bf16, 16384x384)
    // [12582912 .. 13303808)  dbl (fp32, 16384x44)
    // [13303808 .. 16449536)  agate (bf16, 16384x384)
    // [16449536 .. 18022400)  chunkA
    // [18022400 .. 19595264)  chunkH
    // [19595264 .. 19761152)  wcv (bf16, 9*192*192)
    u16* tn_bf    = (u16*)ws;
    u16* t2bf     = (u16*)ws;
    float* hstart = ws + 1572864;
    u16* xz       = (u16*)(ws + 3145728);
    u16* xt_bf    = (u16*)(ws + 9437184);
    float* dbl    = ws + 12582912;
    u16* agate    = (u16*)(ws + 13303808);
    float* chunkA = ws + 16449536;
    float* chunkH = ws + 18022400;
    u16* wcv      = (u16*)(ws + 19595264);

    k_ln<<<Bn * (Ln / 64), 256, 0, stream>>>(x, lnw, lnb, tn_bf);
    k_bgemm<128, 64, Cn, 96, 64, E2, true><<<dim3((Bn * Ln) / 128, E2 / 64), 256, 0, stream>>>(
        tn_bf, inpw, xz);
    k_conv1d<<<(Bn * Ln * (DIn / 4)) / 256, 256, 0, stream>>>(xz, cw, cb, xt_bf);
    k_bgemm<64, 48, DIn, 96, 44, 44, false><<<dim3((Bn * Ln) / 64, 1), 256, 0, stream>>>(
        xt_bf, xpw, dbl);
    k_scan1<<<dim3(DIn / 16, NCn, Bn), 256, 0, stream>>>(xt_bf, dbl, dtw, dtb, alog,
                                                         chunkA, chunkH);
    k_scan15<<<dim3(DIn / 16, Bn), 256, 0, stream>>>(chunkA, chunkH, hstart);
    k_scan2<<<dim3(DIn / 16, NCn, Bn), 256, 0, stream>>>(xt_bf, dbl, dtw, dtb, alog,
                                                         hstart, xz, Dp, agate);
    k_outproj<<<dim3((Bn * Ln) / 128, Cn / 64), 256, 0, stream>>>(agate, Wo, x, t2bf);
    k_cvt_rfw<<<(Cn * Cn * 9 + 255) / 256, 256, 0, stream>>>(rfw, wcv);
    k_conv3<<<dim3(128, Cn / 64), 256, 0, stream>>>(t2bf, wcv, rfb, bnw, bnb, bnm, bnv,
                                                    (float*)d_out);
}

// Round 7
// 241.408 us; speedup vs baseline: 1.1142x; 1.1142x over previous
//
#include <hip/hip_runtime.h>

// MambaSkipConnection: B=4, C=192, H=W=64 (L=4096), DI=384, N=16, RK=12, DCONV=4
// Round 7: x_proj∘dt_proj algebraically fused into one GEMM (W_comb = [dtw@xpw[:12]; xpw[12:44]]);
// softplus computed ONCE in GEMM epilogue (de, de*u stored bf16; B/C fp32);
// scan passes strip dt-dot/softplus; quad-reduce via explicit DPP.

#define Bn 4
#define Cn 192
#define Hn 64
#define Wn 64
#define Ln 4096
#define DIn 384
#define Nst 16
#define RK 12
#define E2 768
#define NCn 64
#define EPSf 1e-5f

typedef __bf16 bf16x8 __attribute__((ext_vector_type(8)));
typedef float f32x4 __attribute__((ext_vector_type(4)));
typedef unsigned short u16;
typedef unsigned int u32;

static __device__ __forceinline__ float sigmoidf_(float v) {
    return 1.f / (1.f + __expf(-v));
}
static __device__ __forceinline__ float softplusf_(float v) {
    return v > 20.f ? v : log1pf(__expf(v));
}
static __device__ __forceinline__ u16 f2bf(float f) {
    u32 u = __float_as_uint(f);
    u32 r = (u + 0x7FFFu + ((u >> 16) & 1u)) >> 16;
    return (u16)r;
}
static __device__ __forceinline__ float bf2f(u16 v) {
    return __uint_as_float(((u32)v) << 16);
}
// quad-perm DPP sum: returns sum over the 4 lanes of each aligned quad (all lanes get it)
static __device__ __forceinline__ float quad_sum_dpp(float p) {
    float a = __int_as_float(__builtin_amdgcn_mov_dpp(__float_as_int(p), 0xB1, 0xF, 0xF, true));
    p += a;
    float b = __int_as_float(__builtin_amdgcn_mov_dpp(__float_as_int(p), 0x4E, 0xF, 0xF, true));
    return p + b;
}

// ---------------------------------------------------------------- K1: LayerNorm -> bf16 tokens
__global__ __launch_bounds__(256) void k_ln(const float* __restrict__ x,
                                            const float* __restrict__ lnw,
                                            const float* __restrict__ lnb,
                                            u16* __restrict__ tn_bf) {
    __shared__ float tile[Cn][65];
    __shared__ float red[2][4][64];
    __shared__ float mean_s[64], rstd_s[64];
    int b = blockIdx.x >> 6;
    int l0 = (blockIdx.x & 63) << 6;
    int tid = threadIdx.x;
    for (int idx = tid; idx < Cn * 64; idx += 256) {
        int c = idx >> 6, ll = idx & 63;
        tile[c][ll] = x[((size_t)(b * Cn + c) << 12) + l0 + ll];
    }
    __syncthreads();
    int ll = tid & 63, grp = tid >> 6;
    float s = 0.f, s2 = 0.f;
    for (int c = grp * 48; c < grp * 48 + 48; ++c) {
        float v = tile[c][ll];
        s += v; s2 += v * v;
    }
    red[0][grp][ll] = s; red[1][grp][ll] = s2;
    __syncthreads();
    if (tid < 64) {
        float m = red[0][0][tid] + red[0][1][tid] + red[0][2][tid] + red[0][3][tid];
        float q = red[1][0][tid] + red[1][1][tid] + red[1][2][tid] + red[1][3][tid];
        m *= (1.f / Cn);
        float var = q * (1.f / Cn) - m * m;
        mean_s[tid] = m;
        rstd_s[tid] = rsqrtf(var + EPSf);
    }
    __syncthreads();
    for (int idx = tid; idx < 64 * Cn; idx += 256) {
        int t = idx / Cn, c = idx - t * Cn;
        float v = (tile[c][t] - mean_s[t]) * rstd_s[t] * lnw[c] + lnb[c];
        tn_bf[(size_t)(b * Ln + l0 + t) * Cn + c] = f2bf(v);
    }
}

// ---------------------------------------------------------------- K2: generic bf16 MFMA GEMM (in_proj)
template <int BM, int BN, int K, int BK, int LDO, bool BOUT>
__global__ __launch_bounds__(256) void k_bgemm(const u16* __restrict__ A,
                                               const float* __restrict__ W,
                                               void* __restrict__ outv) {
    constexpr int PK = BK + 8;
    constexpr int MF = BM / 64;
    constexpr int NF = BN / 16;
    constexpr int NCH = BK / 8;
    constexpr int NQ = BK / 4;
    __shared__ __align__(16) u16 As[BM * PK];
    __shared__ __align__(16) u16 Ws_[BN * PK];
    int m0 = blockIdx.x * BM, n0 = blockIdx.y * BN;
    int tid = threadIdx.x;
    int wid = tid >> 6, lane = tid & 63;
    int lrow = lane & 15, lk8 = (lane >> 4) << 3, rowq = lane >> 4;
    f32x4 acc[MF][NF];
#pragma unroll
    for (int i = 0; i < MF; ++i)
#pragma unroll
        for (int j = 0; j < NF; ++j) acc[i][j] = (f32x4){0.f, 0.f, 0.f, 0.f};
    for (int kt = 0; kt < K / BK; ++kt) {
        int k0 = kt * BK;
        for (int idx = tid; idx < BM * NCH; idx += 256) {
            int r = idx / NCH, c2 = idx - r * NCH;
            *(uint4*)&As[r * PK + c2 * 8] =
                *(const uint4*)&A[(size_t)(m0 + r) * K + k0 + c2 * 8];
        }
        for (int idx = tid; idx < BN * NQ; idx += 256) {
            int r = idx / NQ, q = idx - r * NQ;
            float4 v = *(const float4*)&W[(size_t)(n0 + r) * K + k0 + q * 4];
            ushort4 o;
            o.x = f2bf(v.x); o.y = f2bf(v.y); o.z = f2bf(v.z); o.w = f2bf(v.w);
            *(ushort4*)&Ws_[r * PK + q * 4] = o;
        }
        __syncthreads();
#pragma unroll
        for (int ks = 0; ks < BK / 32; ++ks) {
            bf16x8 a[MF], bfr[NF];
#pragma unroll
            for (int mf = 0; mf < MF; ++mf)
                a[mf] = *(const bf16x8*)&As[(wid * (BM / 4) + mf * 16 + lrow) * PK + ks * 32 + lk8];
#pragma unroll
            for (int nf = 0; nf < NF; ++nf)
                bfr[nf] = *(const bf16x8*)&Ws_[(nf * 16 + lrow) * PK + ks * 32 + lk8];
#pragma unroll
            for (int mf = 0; mf < MF; ++mf)
#pragma unroll
                for (int nf = 0; nf < NF; ++nf)
                    acc[mf][nf] = __builtin_amdgcn_mfma_f32_16x16x32_bf16(a[mf], bfr[nf],
                                                                          acc[mf][nf], 0, 0, 0);
        }
        __syncthreads();
    }
#pragma unroll
    for (int mf = 0; mf < MF; ++mf)
#pragma unroll
        for (int nf = 0; nf < NF; ++nf) {
            int col = n0 + nf * 16 + lrow;
            int rbase = m0 + wid * (BM / 4) + mf * 16 + rowq * 4;
#pragma unroll
            for (int r = 0; r < 4; ++r) {
                if (BOUT)
                    ((u16*)outv)[(size_t)(rbase + r) * LDO + col] = f2bf(acc[mf][nf][r]);
                else
                    ((float*)outv)[(size_t)(rbase + r) * LDO + col] = acc[mf][nf][r];
            }
        }
}

// ---------------------------------------------------------------- K2b: W_comb = [dtw@xpw[:12] (384); xpw[12:44] (32)]
__global__ __launch_bounds__(256) void k_wcomb(const float* __restrict__ xpw,
                                               const float* __restrict__ dtw,
                                               float* __restrict__ wcomb) {
    int g = blockIdx.x * 256 + threadIdx.x;
    if (g >= 416 * 384) return;
    int row = g / 384, k = g - row * 384;
    float v;
    if (row < 384) {
        v = 0.f;
#pragma unroll
        for (int r = 0; r < RK; ++r)
            v = fmaf(dtw[row * RK + r], xpw[r * 384 + k], v);
    } else {
        v = xpw[(RK + row - 384) * 384 + k];
    }
    wcomb[g] = v;
}

// ---------------------------------------------------------------- K2c: combined projection GEMM
// out cols 0..383 -> de=softplus(v+dtb) (bf16) + de*u (bf16); cols 384..415 -> B/C fp32.
__global__ __launch_bounds__(256) void k_proj(const u16* __restrict__ xt_bf,
                                              const float* __restrict__ W,
                                              const float* __restrict__ dtb,
                                              u16* __restrict__ de_bf,
                                              u16* __restrict__ dux_bf,
                                              float* __restrict__ bc) {
    constexpr int BM = 128, BN = 64, K = DIn, BK = 96;
    constexpr int PK = BK + 8;
    constexpr int NCH = BK / 8;
    constexpr int NQ = BK / 4;
    __shared__ __align__(16) u16 As[BM * PK];
    __shared__ __align__(16) u16 Ws_[BN * PK];
    int m0 = blockIdx.x * BM, n0 = blockIdx.y * BN;
    int tid = threadIdx.x;
    int wid = tid >> 6, lane = tid & 63;
    int lrow = lane & 15, lk8 = (lane >> 4) << 3, rowq = lane >> 4;
    f32x4 acc[2][4];
#pragma unroll
    for (int i = 0; i < 2; ++i)
#pragma unroll
        for (int j = 0; j < 4; ++j) acc[i][j] = (f32x4){0.f, 0.f, 0.f, 0.f};
    for (int kt = 0; kt < K / BK; ++kt) {
        int k0 = kt * BK;
        for (int idx = tid; idx < BM * NCH; idx += 256) {
            int r = idx / NCH, c2 = idx - r * NCH;
            *(uint4*)&As[r * PK + c2 * 8] =
                *(const uint4*)&xt_bf[(size_t)(m0 + r) * K + k0 + c2 * 8];
        }
        for (int idx = tid; idx < BN * NQ; idx += 256) {
            int r = idx / NQ, q = idx - r * NQ;
            ushort4 o = make_ushort4(0, 0, 0, 0);
            if (n0 + r < 416) {
                float4 v = *(const float4*)&W[(size_t)(n0 + r) * K + k0 + q * 4];
                o.x = f2bf(v.x); o.y = f2bf(v.y); o.z = f2bf(v.z); o.w = f2bf(v.w);
            }
            *(ushort4*)&Ws_[r * PK + q * 4] = o;
        }
        __syncthreads();
#pragma unroll
        for (int ks = 0; ks < BK / 32; ++ks) {
            bf16x8 a[2], bfr[4];
#pragma unroll
            for (int mf = 0; mf < 2; ++mf)
                a[mf] = *(const bf16x8*)&As[(wid * 32 + mf * 16 + lrow) * PK + ks * 32 + lk8];
#pragma unroll
            for (int nf = 0; nf < 4; ++nf)
                bfr[nf] = *(const bf16x8*)&Ws_[(nf * 16 + lrow) * PK + ks * 32 + lk8];
#pragma unroll
            for (int mf = 0; mf < 2; ++mf)
#pragma unroll
                for (int nf = 0; nf < 4; ++nf)
                    acc[mf][nf] = __builtin_amdgcn_mfma_f32_16x16x32_bf16(a[mf], bfr[nf],
                                                                          acc[mf][nf], 0, 0, 0);
        }
        __syncthreads();
    }
#pragma unroll
    for (int mf = 0; mf < 2; ++mf)
#pragma unroll
        for (int nf = 0; nf < 4; ++nf) {
            int col = n0 + nf * 16 + lrow;
            int rbase = m0 + wid * 32 + mf * 16 + rowq * 4;
            if (col < 384) {
                float dtbc = dtb[col];
#pragma unroll
                for (int r = 0; r < 4; ++r) {
                    int m = rbase + r;
                    float de = softplusf_(acc[mf][nf][r] + dtbc);
                    float u = bf2f(xt_bf[(size_t)m * DIn + col]);
                    de_bf[(size_t)m * DIn + col] = f2bf(de);
                    dux_bf[(size_t)m * DIn + col] = f2bf(de * u);
                }
            } else if (col < 416) {
#pragma unroll
                for (int r = 0; r < 4; ++r) {
                    int m = rbase + r;
                    bc[(size_t)m * 32 + col - 384] = acc[mf][nf][r];
                }
            }
        }
}

// ---------------------------------------------------------------- K3: causal depthwise conv1d + SiLU (bf16 in/out)
__global__ __launch_bounds__(256) void k_conv1d(const u16* __restrict__ xz,
                                                const float* __restrict__ cw,
                                                const float* __restrict__ cb,
                                                u16* __restrict__ xt_bf) {
    int g = blockIdx.x * 256 + threadIdx.x;
    int m = g / 96, dq = g - m * 96;
    int d = dq << 2;
    int l = m & (Ln - 1);
    float w_[4][4];
    *(float4*)&w_[0][0] = *(const float4*)&cw[(d + 0) << 2];
    *(float4*)&w_[1][0] = *(const float4*)&cw[(d + 1) << 2];
    *(float4*)&w_[2][0] = *(const float4*)&cw[(d + 2) << 2];
    *(float4*)&w_[3][0] = *(const float4*)&cw[(d + 3) << 2];
    float4 bv = *(const float4*)&cb[d];
    float o_[4] = {bv.x, bv.y, bv.z, bv.w};
    const u16* base = xz + (size_t)m * E2 + d;
#pragma unroll
    for (int j = 0; j < 4; ++j) {
        if (l >= j) {
            ushort4 in4 = *(const ushort4*)(base - (size_t)j * E2);
            o_[0] += bf2f(in4.x) * w_[0][3 - j];
            o_[1] += bf2f(in4.y) * w_[1][3 - j];
            o_[2] += bf2f(in4.z) * w_[2][3 - j];
            o_[3] += bf2f(in4.w) * w_[3][3 - j];
        }
    }
    ushort4 rb;
    rb.x = f2bf(o_[0] * sigmoidf_(o_[0]));
    rb.y = f2bf(o_[1] * sigmoidf_(o_[1]));
    rb.z = f2bf(o_[2] * sigmoidf_(o_[2]));
    rb.w = f2bf(o_[3] * sigmoidf_(o_[3]));
    *(ushort4*)&xt_bf[(size_t)m * DIn + d] = rb;
}

// ---------------------------------------------------------------- K6a: scan pass 1 (reads precomputed de/dux/B)
__global__ __launch_bounds__(256) void k_scan1(const u16* __restrict__ de_bf,
                                               const u16* __restrict__ dux_bf,
                                               const float* __restrict__ bc,
                                               const float* __restrict__ alog,
                                               float* __restrict__ chunkA,
                                               float* __restrict__ chunkH) {
    __shared__ __align__(16) float ds_de[16][20], ds_dux[16][20], ds_bt[16][20];
    int dg = blockIdx.x, c = blockIdx.y, b = blockIdx.z;
    int tid = threadIdx.x;
    int dl = tid >> 4, n = tid & 15;
    int trow = dl, dd = n;
    float Av = -__expf(alog[(dg * 16 + dl) * Nst + n]);
    float h = 0.f, ap = 1.f;
    for (int sub = 0; sub < 4; ++sub) {
        int row = b * Ln + c * 64 + sub * 16 + trow;
        size_t doff = (size_t)row * DIn + dg * 16 + dd;
        ds_de[dd][trow] = bf2f(de_bf[doff]);
        ds_dux[dd][trow] = bf2f(dux_bf[doff]);
        ds_bt[dd][trow] = bc[(size_t)row * 32 + dd];
        __syncthreads();
#pragma unroll
        for (int t4 = 0; t4 < 4; ++t4) {
            f32x4 de4 = *(const f32x4*)&ds_de[dl][t4 * 4];
            f32x4 dux4 = *(const f32x4*)&ds_dux[dl][t4 * 4];
            f32x4 bb4 = *(const f32x4*)&ds_bt[n][t4 * 4];
#pragma unroll
            for (int j = 0; j < 4; ++j) {
                float a = __expf(de4[j] * Av);
                ap *= a;
                h = fmaf(a, h, dux4[j] * bb4[j]);
            }
        }
        __syncthreads();
    }
    size_t base = (size_t)(b * NCn + c) * (DIn * Nst) + dg * 256;
    chunkA[base + tid] = ap;
    chunkH[base + tid] = h;
}

// ---------------------------------------------------------------- K6b: scan pass 1.5 — chunk-start states
__global__ __launch_bounds__(256) void k_scan15(const float* __restrict__ chunkA,
                                                const float* __restrict__ chunkH,
                                                float* __restrict__ hstart) {
    int dg = blockIdx.x, b = blockIdx.y;
    int tid = threadIdx.x;
    size_t off = (size_t)b * NCn * (DIn * Nst) + dg * 256 + tid;
    float h = 0.f;
    for (int c0 = 0; c0 < NCn; c0 += 8) {
        float Ar[8], Hr[8];
#pragma unroll
        for (int j = 0; j < 8; ++j) {
            Ar[j] = chunkA[off + (size_t)(c0 + j) * (DIn * Nst)];
            Hr[j] = chunkH[off + (size_t)(c0 + j) * (DIn * Nst)];
        }
#pragma unroll
        for (int j = 0; j < 8; ++j) {
            hstart[off + (size_t)(c0 + j) * (DIn * Nst)] = h;
            h = fmaf(Ar[j], h, Hr[j]);
        }
    }
}

// ---------------------------------------------------------------- K6c: scan pass 2 (gate fused; DPP quad-reduce)
__global__ __launch_bounds__(256) void k_scan2(const u16* __restrict__ de_bf,
                                               const u16* __restrict__ dux_bf,
                                               const float* __restrict__ bc,
                                               const float* __restrict__ alog,
                                               const float* __restrict__ hstart,
                                               const u16* __restrict__ xt_bf,
                                               const u16* __restrict__ xz,
                                               const float* __restrict__ Dp,
                                               u16* __restrict__ agate) {
    __shared__ __align__(16) float ds_de[16][20], ds_dux[16][20], ds_bt[16][20], ds_ct[16][20];
    __shared__ __align__(16) float pq[16][16][4];
    int dg = blockIdx.x, c = blockIdx.y, b = blockIdx.z;
    int tid = threadIdx.x;
    int dl = tid >> 4, n = tid & 15;
    int trow = dl, dd = n;
    int aq = n >> 2, bq = n & 3;
    float Av = -__expf(alog[(dg * 16 + dl) * Nst + n]);
    float Dr = Dp[dg * 16 + dd];
    size_t base = (size_t)(b * NCn + c) * (DIn * Nst) + dg * 256;
    float h = hstart[base + tid];
    for (int sub = 0; sub < 4; ++sub) {
        int row = b * Ln + c * 64 + sub * 16 + trow;
        size_t doff = (size_t)row * DIn + dg * 16 + dd;
        ds_de[dd][trow] = bf2f(de_bf[doff]);
        ds_dux[dd][trow] = bf2f(dux_bf[doff]);
        ds_bt[dd][trow] = bc[(size_t)row * 32 + dd];
        ds_ct[dd][trow] = bc[(size_t)row * 32 + 16 + dd];
        float uu = bf2f(xt_bf[doff]);
        float zz = bf2f(xz[(size_t)row * E2 + DIn + dg * 16 + dd]);
        __syncthreads();
        float P[4] = {0.f, 0.f, 0.f, 0.f};
#pragma unroll
        for (int t4 = 0; t4 < 4; ++t4) {
            f32x4 de4 = *(const f32x4*)&ds_de[dl][t4 * 4];
            f32x4 dux4 = *(const f32x4*)&ds_dux[dl][t4 * 4];
            f32x4 bb4 = *(const f32x4*)&ds_bt[n][t4 * 4];
            f32x4 ct4 = *(const f32x4*)&ds_ct[n][t4 * 4];
#pragma unroll
            for (int j = 0; j < 4; ++j) {
                float a = __expf(de4[j] * Av);
                h = fmaf(a, h, dux4[j] * bb4[j]);
                float p = quad_sum_dpp(h * ct4[j]);   // sum over n within quad
                P[t4] = (bq == j) ? p : P[t4];
            }
        }
        // lane (dl, n=4*aq+bq) holds quad-aq partial for tokens {bq,4+bq,8+bq,12+bq}
#pragma unroll
        for (int tt = 0; tt < 4; ++tt)
            pq[tt * 4 + bq][dl][aq] = P[tt];
        __syncthreads();
        f32x4 p4 = *(const f32x4*)&pq[trow][dd][0];
        float y = (p4[0] + p4[1]) + (p4[2] + p4[3]);
        float ga = (y + uu * Dr) * (zz * sigmoidf_(zz));
        agate[doff] = f2bf(ga);
    }
}

// ---------------------------------------------------------------- K7: out_proj GEMM (bf16 A) + residual -> t2bf
__global__ __launch_bounds__(256) void k_outproj(const u16* __restrict__ agate,
                                                 const float* __restrict__ Wo,
                                                 const float* __restrict__ x,
                                                 u16* __restrict__ t2bf) {
    constexpr int BM = 128, BN = 64, K = DIn, BK = 96;
    constexpr int PK = BK + 8;
    constexpr int NCH = BK / 8;
    constexpr int NQ = BK / 4;
    __shared__ __align__(16) u16 As[BM * PK];
    __shared__ __align__(16) u16 Ws_[BN * PK];
    int m0 = blockIdx.x * BM, n0 = blockIdx.y * BN;
    int tid = threadIdx.x;
    int wid = tid >> 6, lane = tid & 63;
    int lrow = lane & 15, lk8 = (lane >> 4) << 3, rowq = lane >> 4;
    f32x4 acc[2][4];
#pragma unroll
    for (int i = 0; i < 2; ++i)
#pragma unroll
        for (int j = 0; j < 4; ++j) acc[i][j] = (f32x4){0.f, 0.f, 0.f, 0.f};
    for (int kt = 0; kt < K / BK; ++kt) {
        int k0 = kt * BK;
        for (int idx = tid; idx < BM * NCH; idx += 256) {
            int r = idx / NCH, c2 = idx - r * NCH;
            *(uint4*)&As[r * PK + c2 * 8] =
                *(const uint4*)&agate[(size_t)(m0 + r) * K + k0 + c2 * 8];
        }
        for (int idx = tid; idx < BN * NQ; idx += 256) {
            int r = idx / NQ, q = idx - r * NQ;
            float4 v = *(const float4*)&Wo[(size_t)(n0 + r) * K + k0 + q * 4];
            ushort4 o;
            o.x = f2bf(v.x); o.y = f2bf(v.y); o.z = f2bf(v.z); o.w = f2bf(v.w);
            *(ushort4*)&Ws_[r * PK + q * 4] = o;
        }
        __syncthreads();
#pragma unroll
        for (int ks = 0; ks < BK / 32; ++ks) {
            bf16x8 a[2], bfr[4];
#pragma unroll
            for (int mf = 0; mf < 2; ++mf)
                a[mf] = *(const bf16x8*)&As[(wid * 32 + mf * 16 + lrow) * PK + ks * 32 + lk8];
#pragma unroll
            for (int nf = 0; nf < 4; ++nf)
                bfr[nf] = *(const bf16x8*)&Ws_[(nf * 16 + lrow) * PK + ks * 32 + lk8];
#pragma unroll
            for (int mf = 0; mf < 2; ++mf)
#pragma unroll
                for (int nf = 0; nf < 4; ++nf)
                    acc[mf][nf] = __builtin_amdgcn_mfma_f32_16x16x32_bf16(a[mf], bfr[nf],
                                                                          acc[mf][nf], 0, 0, 0);
        }
        __syncthreads();
    }
#pragma unroll
    for (int mf = 0; mf < 2; ++mf)
#pragma unroll
        for (int nf = 0; nf < 4; ++nf) {
            int col = n0 + nf * 16 + lrow;
            int rbase = m0 + wid * 32 + mf * 16 + rowq * 4;
#pragma unroll
            for (int r = 0; r < 4; ++r) {
                int m = rbase + r;
                int b = m >> 12, l = m & 4095;
                float v = acc[mf][nf][r] + x[((size_t)(b * Cn + col) << 12) + l];
                t2bf[(size_t)m * Cn + col] = f2bf(v);
            }
        }
}

// ---------------------------------------------------------------- K8a: rfw fp32 [co][ci][tap] -> bf16 [tap][co][ci]
__global__ __launch_bounds__(256) void k_cvt_rfw(const float* __restrict__ rfw,
                                                 u16* __restrict__ wcv) {
    int g = blockIdx.x * 256 + threadIdx.x;
    if (g >= Cn * Cn * 9) return;
    int tap = g / (Cn * Cn);
    int rem = g - tap * (Cn * Cn);
    int co = rem / Cn, ci = rem - co * Cn;
    wcv[g] = f2bf(rfw[((size_t)co * Cn + ci) * 9 + tap]);
}

// ---------------------------------------------------------------- K8: conv3x3 + BN + ReLU, bf16 MFMA implicit GEMM
__global__ __launch_bounds__(256) void k_conv3(const u16* __restrict__ t2bf,
                                               const u16* __restrict__ wcv,
                                               const float* __restrict__ rfb,
                                               const float* __restrict__ bnw,
                                               const float* __restrict__ bnb,
                                               const float* __restrict__ bnm,
                                               const float* __restrict__ bnv,
                                               float* __restrict__ out) {
    __shared__ __align__(16) u16 in_s[4 * 66 * 40];
    __shared__ __align__(16) u16 w_s[9 * 64 * 40];
    int mt = blockIdx.x;
    int n0 = blockIdx.y << 6;
    int b = mt >> 5;
    int h0 = (mt & 31) << 1;
    int hw0 = h0 << 6;
    int tid = threadIdx.x;
    int wid = tid >> 6, lane = tid & 63;
    int lrow = lane & 15, lk8 = (lane >> 4) << 3, l4 = (lane >> 4) << 2;

    for (int idx = tid; idx < 4 * 40; idx += 256) {
        int rl = idx / 40, k = idx - rl * 40;
        in_s[(rl * 66 + 0) * 40 + k] = 0;
        in_s[(rl * 66 + 65) * 40 + k] = 0;
    }

    int s0 = wid * 32 + lrow;
    int s1 = s0 + 16;
    int abase0 = ((s0 >> 6) * 66 + (s0 & 63)) * 40 + lk8;
    int abase1 = ((s1 >> 6) * 66 + (s1 & 63)) * 40 + lk8;
    int bbase = lrow * 40 + lk8;

    f32x4 acc[2][4];
#pragma unroll
    for (int i = 0; i < 2; ++i)
#pragma unroll
        for (int j = 0; j < 4; ++j) acc[i][j] = (f32x4){0.f, 0.f, 0.f, 0.f};

    int wq = tid >> 2, cq = (tid & 3) << 3;
    for (int ci0 = 0; ci0 < Cn; ci0 += 32) {
        __syncthreads();
#pragma unroll
        for (int rl = 0; rl < 4; ++rl) {
            int gr = h0 - 1 + rl;
            uint4 v = make_uint4(0u, 0u, 0u, 0u);
            if (gr >= 0 && gr < Hn)
                v = *(const uint4*)&t2bf[(size_t)((b << 12) + (gr << 6) + wq) * Cn + ci0 + cq];
            *(uint4*)&in_s[(rl * 66 + wq + 1) * 40 + cq] = v;
        }
#pragma unroll
        for (int tap = 0; tap < 9; ++tap) {
            int co = tid >> 2;
            uint4 v = *(const uint4*)&wcv[((size_t)tap * Cn + n0 + co) * Cn + ci0 + cq];
            *(uint4*)&w_s[(tap * 64 + co) * 40 + cq] = v;
        }
        __syncthreads();
#pragma unroll
        for (int kh = 0; kh < 3; ++kh) {
#pragma unroll
            for (int kw = 0; kw < 3; ++kw) {
                int aoff = (kh * 66 + kw) * 40;
                bf16x8 a0 = *(const bf16x8*)&in_s[abase0 + aoff];
                bf16x8 a1 = *(const bf16x8*)&in_s[abase1 + aoff];
                int boff = (kh * 3 + kw) * 2560;
#pragma unroll
                for (int nf = 0; nf < 4; ++nf) {
                    bf16x8 bb = *(const bf16x8*)&w_s[bbase + nf * 640 + boff];
                    acc[0][nf] = __builtin_amdgcn_mfma_f32_16x16x32_bf16(a0, bb, acc[0][nf], 0, 0, 0);
                    acc[1][nf] = __builtin_amdgcn_mfma_f32_16x16x32_bf16(a1, bb, acc[1][nf], 0, 0, 0);
                }
            }
        }
    }
#pragma unroll
    for (int nf = 0; nf < 4; ++nf) {
        int co = n0 + nf * 16 + lrow;
        float sc = bnw[co] * rsqrtf(bnv[co] + EPSf);
        float sf = (rfb[co] - bnm[co]) * sc + bnb[co];
        size_t obase = ((size_t)(b * Cn + co) << 12) + hw0;
#pragma unroll
        for (int mf = 0; mf < 2; ++mf) {
            int sb = wid * 32 + mf * 16 + l4;
            float4 o;
            o.x = fmaxf(acc[mf][nf][0] * sc + sf, 0.f);
            o.y = fmaxf(acc[mf][nf][1] * sc + sf, 0.f);
            o.z = fmaxf(acc[mf][nf][2] * sc + sf, 0.f);
            o.w = fmaxf(acc[mf][nf][3] * sc + sf, 0.f);
            *(float4*)&out[obase + sb] = o;
        }
    }
}

// ----------------------------------------------------------------
extern "C" void kernel_launch(void* const* d_in, const int* in_sizes, int n_in,
                              void* d_out, int out_size, void* d_ws, size_t ws_size,
                              hipStream_t stream) {
    const float* x    = (const float*)d_in[0];
    const float* lnw  = (const float*)d_in[1];
    const float* lnb  = (const float*)d_in[2];
    const float* inpw = (const float*)d_in[3];
    const float* cw   = (const float*)d_in[4];
    const float* cb   = (const float*)d_in[5];
    const float* xpw  = (const float*)d_in[6];
    const float* dtw  = (const float*)d_in[7];
    const float* dtb  = (const float*)d_in[8];
    const float* alog = (const float*)d_in[9];
    const float* Dp   = (const float*)d_in[10];
    const float* Wo   = (const float*)d_in[11];
    const float* rfw  = (const float*)d_in[12];
    const float* rfb  = (const float*)d_in[13];
    const float* bnw  = (const float*)d_in[14];
    const float* bnb  = (const float*)d_in[15];
    const float* bnm  = (const float*)d_in[16];
    const float* bnv  = (const float*)d_in[17];

    float* ws = (float*)d_ws;
    // region map (floats):
    // [0 .. 1572864)          tn_bf (bf16) -> t2bf (bf16)
    // [1572864 .. 3145728)    hstart
    // [3145728 .. 9437184)    xz (bf16, 16384x768)
    // [9437184 .. 12582912)   xt_bf (bf16)
    // [12582912 .. 15728640)  de_bf (bf16)
    // [15728640 .. 18874368)  dux_bf (bf16)
    // [18874368 .. 19398656)  bc (fp32, 16384x32)
    // [19398656 .. 22544384)  agate (bf16)
    // [22544384 .. 24117248)  chunkA
    // [24117248 .. 25690112)  chunkH
    // [25690112 .. 25856000)  wcv (bf16)
    // [25856000 .. 26015744)  wcomb (fp32, 416x384)
    u16* tn_bf    = (u16*)ws;
    u16* t2bf     = (u16*)ws;
    float* hstart = ws + 1572864;
    u16* xz       = (u16*)(ws + 3145728);
    u16* xt_bf    = (u16*)(ws + 9437184);
    u16* de_bf    = (u16*)(ws + 12582912);
    u16* dux_bf   = (u16*)(ws + 15728640);
    float* bc     = ws + 18874368;
    u16* agate    = (u16*)(ws + 19398656);
    float* chunkA = ws + 22544384;
    float* chunkH = ws + 24117248;
    u16* wcv      = (u16*)(ws + 25690112);
    float* wcomb  = ws + 25856000;

    k_ln<<<Bn * (Ln / 64), 256, 0, stream>>>(x, lnw, lnb, tn_bf);
    k_bgemm<128, 64, Cn, 96, E2, true><<<dim3((Bn * Ln) / 128, E2 / 64), 256, 0, stream>>>(
        tn_bf, inpw, xz);
    k_conv1d<<<(Bn * Ln * (DIn / 4)) / 256, 256, 0, stream>>>(xz, cw, cb, xt_bf);
    k_wcomb<<<(416 * 384 + 255) / 256, 256, 0, stream>>>(xpw, dtw, wcomb);
    k_proj<<<dim3((Bn * Ln) / 128, 7), 256, 0, stream>>>(xt_bf, wcomb, dtb,
                                                         de_bf, dux_bf, bc);
    k_scan1<<<dim3(DIn / 16, NCn, Bn), 256, 0, stream>>>(de_bf, dux_bf, bc, alog,
                                                         chunkA, chunkH);
    k_scan15<<<dim3(DIn / 16, Bn), 256, 0, stream>>>(chunkA, chunkH, hstart);
    k_scan2<<<dim3(DIn / 16, NCn, Bn), 256, 0, stream>>>(de_bf, dux_bf, bc, alog,
                                                         hstart, xt_bf, xz, Dp, agate);
    k_outproj<<<dim3((Bn * Ln) / 128, Cn / 64), 256, 0, stream>>>(agate, Wo, x, t2bf);
    k_cvt_rfw<<<(Cn * Cn * 9 + 255) / 256, 256, 0, stream>>>(rfw, wcv);
    k_conv3<<<dim3(128, Cn / 64), 256, 0, stream>>>(t2bf, wcv, rfb, bnw, bnb, bnm, bnv,
                                                    (float*)d_out);
}